// Round 1
// 8443.078 us; speedup vs baseline: 1.5833x; 1.5833x over previous
//
#include <hip/hip_runtime.h>
#include <math.h>

#define BB 4
#define TT 4096
#define DIMW 1024
#define HID 1536
#define HID2 3072
#define KC 4
#define SSEG 16
#define LSEG 256
#define DD 384
#define NCH 64          // scan chunks per batch
#define CHL 64          // tokens per chunk (NCH*CHL == TT)
#define TH  ((size_t)TT*(size_t)HID)   // elements in one T x HID slot

// =====================================================================
// fp32 GEMM: C[m,n] = sum_k A[m,k] * W[n,k]   (both row-major, read along K)
// fp32 accumulation. Tile TMxTN (128x128 / 128x64 / 64x64), BK=16,
// 256 threads, per-thread (TM/16)x(TN/16) floats in groups of 4:
//   row(i) = (i>>2)*64 + ty*4 + (i&3),  col(j) = (j>>2)*64 + tx*4 + (j&3)
// LDS is k-major (As[k][row]) so compute reads are float4; the per-thread
// column groups {tx*4, 64+tx*4} give 16 lanes x 16B spanning 256B
// => 2 lanes/bank-group => conflict-free (2-way is free on gfx950).
// Register-prefetch double buffering hides global latency under compute.
// MODE 0: plain store to C0 (row stride Nout)
// MODE 1: split columns [0,HID)->C0, [HID,2HID)->C1 (both row stride HID)
// MODE 2: C0[m*Nout+n] = silu(acc) * X[m*Nout+n]
// =====================================================================
template<int MODE, int TM, int TN>
__global__ __launch_bounds__(256) void gemm32(const float* __restrict__ A,
                                              const float* __restrict__ W,
                                              float* __restrict__ C0,
                                              float* __restrict__ C1,
                                              const float* __restrict__ X,
                                              int M, int Nout, int Kd)
{
    constexpr int GM = TM / 64;
    constexpr int GN = TN / 64;
    constexpr int AF4 = TM * 4;          // float4s per A k-tile (TM rows x 16 k)
    constexpr int WF4 = TN * 4;
    constexpr int ALOOP = (AF4 + 255) / 256;
    constexpr int WLOOP = (WF4 + 255) / 256;

    __shared__ float As[16][TM];
    __shared__ float Bs[16][TN];

    const int tid = threadIdx.x;
    const int m0 = blockIdx.x * TM;
    const int n0 = blockIdx.y * TN;
    const int tx = tid & 15, ty = tid >> 4;

    float acc[GM * 4][GN * 4];
#pragma unroll
    for (int i = 0; i < GM * 4; i++)
#pragma unroll
        for (int j = 0; j < GN * 4; j++) acc[i][j] = 0.0f;

    float4 aReg[ALOOP], wReg[WLOOP];

    auto issueLoads = [&](int k0) {
#pragma unroll
        for (int u = 0; u < ALOOP; u++) {
            const int idx = tid + u * 256;
            float4 v = make_float4(0.f, 0.f, 0.f, 0.f);
            if (idx < AF4) {
                const int row = idx >> 2, kq = (idx & 3) * 4;
                const long ar = (long)(m0 + row);
                if (ar < M) v = *(const float4*)(A + ar * (long)Kd + (k0 + kq));
            }
            aReg[u] = v;
        }
#pragma unroll
        for (int u = 0; u < WLOOP; u++) {
            const int idx = tid + u * 256;
            float4 v = make_float4(0.f, 0.f, 0.f, 0.f);
            if (idx < WF4) {
                const int row = idx >> 2, kq = (idx & 3) * 4;
                const long wr = (long)(n0 + row);
                v = *(const float4*)(W + wr * (long)Kd + (k0 + kq));
            }
            wReg[u] = v;
        }
    };
    auto writeLDS = [&]() {
#pragma unroll
        for (int u = 0; u < ALOOP; u++) {
            const int idx = tid + u * 256;
            if (idx < AF4) {
                const int row = idx >> 2, kq = (idx & 3) * 4;
                As[kq + 0][row] = aReg[u].x;
                As[kq + 1][row] = aReg[u].y;
                As[kq + 2][row] = aReg[u].z;
                As[kq + 3][row] = aReg[u].w;
            }
        }
#pragma unroll
        for (int u = 0; u < WLOOP; u++) {
            const int idx = tid + u * 256;
            if (idx < WF4) {
                const int row = idx >> 2, kq = (idx & 3) * 4;
                Bs[kq + 0][row] = wReg[u].x;
                Bs[kq + 1][row] = wReg[u].y;
                Bs[kq + 2][row] = wReg[u].z;
                Bs[kq + 3][row] = wReg[u].w;
            }
        }
    };

    issueLoads(0);
    writeLDS();
    __syncthreads();

    const int NT = Kd / 16;
    for (int t = 0; t < NT; t++) {
        if (t + 1 < NT) issueLoads((t + 1) * 16);
#pragma unroll
        for (int k = 0; k < 16; k++) {
            float a[GM * 4], b[GN * 4];
#pragma unroll
            for (int g = 0; g < GM; g++) {
                const float4 t4 = *(const float4*)&As[k][g * 64 + ty * 4];
                a[g * 4 + 0] = t4.x; a[g * 4 + 1] = t4.y;
                a[g * 4 + 2] = t4.z; a[g * 4 + 3] = t4.w;
            }
#pragma unroll
            for (int g = 0; g < GN; g++) {
                const float4 t4 = *(const float4*)&Bs[k][g * 64 + tx * 4];
                b[g * 4 + 0] = t4.x; b[g * 4 + 1] = t4.y;
                b[g * 4 + 2] = t4.z; b[g * 4 + 3] = t4.w;
            }
#pragma unroll
            for (int i = 0; i < GM * 4; i++)
#pragma unroll
                for (int j = 0; j < GN * 4; j++) acc[i][j] += a[i] * b[j];
        }
        __syncthreads();
        if (t + 1 < NT) {
            writeLDS();
            __syncthreads();
        }
    }

#pragma unroll
    for (int i = 0; i < GM * 4; i++) {
        const int m = m0 + (i >> 2) * 64 + ty * 4 + (i & 3);
        if (m >= M) continue;
#pragma unroll
        for (int j = 0; j < GN * 4; j++) {
            const int n = n0 + (j >> 2) * 64 + tx * 4 + (j & 3);
            if constexpr (MODE == 1) {
                if (n < HID) C0[(long)m * HID + n] = acc[i][j];
                else         C1[(long)m * HID + (n - HID)] = acc[i][j];
            } else if constexpr (MODE == 2) {
                double g = (double)acc[i][j];
                double v = (g / (1.0 + exp(-g))) * (double)X[(long)m * Nout + n];
                C0[(long)m * Nout + n] = (float)v;
            } else {
                C0[(long)m * Nout + n] = acc[i][j];
            }
        }
    }
}

// softplus(forget_base) per channel (once)
__global__ __launch_bounds__(256) void spb_kernel(const float* __restrict__ fb,
                                                  double* __restrict__ spb)
{
    int h = blockIdx.x * 256 + threadIdx.x;
    if (h < HID) {
        double xv = (double)fb[h];
        spb[h] = log1p(exp(xv));
    }
}

// concat wk (DD x HID) and wv (DD x HID) -> wkv (2DD x HID), once
__global__ __launch_bounds__(256) void catkv_kernel(const float* __restrict__ wk,
                                                    const float* __restrict__ wv,
                                                    float* __restrict__ wkv)
{
    const int half = DD * HID;
    int i = blockIdx.x * 256 + threadIdx.x;
    if (i < half) wkv[i] = wk[i];
    else if (i < 2 * half) wkv[i] = wv[i - half];
}

// causal depthwise conv (one batch): out[t,h] = cb[h] + sum_j cw[h,j]*x[t-3+j,h]
__global__ __launch_bounds__(256) void conv_kernel(const float* __restrict__ xin,
                                                   const float* __restrict__ cw,
                                                   const float* __restrict__ cb,
                                                   float* __restrict__ outp)
{
    size_t i = (size_t)blockIdx.x * 256 + threadIdx.x;
    if (i >= TH) return;
    int h = (int)(i % HID);
    int t = (int)(i / HID);
    double acc = (double)cb[h];
#pragma unroll
    for (int j = 0; j < KC; j++) {
        int tt = t - (KC - 1) + j;
        if (tt >= 0) acc += (double)cw[h * KC + j] * (double)xin[(size_t)tt * HID + h];
    }
    outp[i] = (float)acc;
}

// raw forget(fg)/inp(ip) (+bias) -> alpha, xh2 : fully in-place, reads xh1
__global__ __launch_bounds__(256) void alpha_xh2_kernel(float* __restrict__ fg,
                                                        float* __restrict__ ip,
                                                        const float* __restrict__ xh1,
                                                        const double* __restrict__ spb,
                                                        const float* __restrict__ gb)
{
    size_t i = (size_t)blockIdx.x * 256 + threadIdx.x;
    if (i >= TH) return;
    int h = (int)(i % HID);
    double f  = (double)fg[i] + (double)gb[h];
    double g2 = (double)ip[i] + (double)gb[HID + h];
    double sigf = 1.0 / (1.0 + exp(-f));
    double alpha = exp(-8.0 * spb[h] * sigf);
    double s2 = sqrt(1.0 - alpha * alpha + 1e-6);
    double sigi = 1.0 / (1.0 + exp(-g2));
    double x1 = (double)xh1[i];
    fg[i] = (float)alpha;
    ip[i] = (float)(s2 * sigi * x1);
}

// scan pass1 (one batch): per (h,chunk) local prefix value + alpha product
__global__ __launch_bounds__(256) void scan1_kernel(const float* __restrict__ alpha,
                                                    const float* __restrict__ xh2,
                                                    double* __restrict__ cA,
                                                    double* __restrict__ cB)
{
    int idx = blockIdx.x * 256 + threadIdx.x;  // c*HID + h
    if (idx >= NCH * HID) return;
    int h = idx % HID;
    int c = idx / HID;
    size_t base = (size_t)c * CHL * HID + h;
    double aP = 1.0, bV = 0.0;
    for (int i = 0; i < CHL; i++) {
        double a  = (double)alpha[base + (size_t)i * HID];
        double xv = (double)xh2 [base + (size_t)i * HID];
        bV = a * bV + xv;
        aP *= a;
    }
    size_t o = (size_t)c * HID + h;
    cA[o] = aP;
    cB[o] = bV;
}

// scan pass2 (one batch): chunk carry-in per h
__global__ __launch_bounds__(256) void scan2_kernel(const double* __restrict__ cA,
                                                    const double* __restrict__ cB,
                                                    double* __restrict__ cH0)
{
    int h = blockIdx.x * 256 + threadIdx.x;
    if (h >= HID) return;
    double carry = 0.0;
    for (int c = 0; c < NCH; c++) {
        size_t o = (size_t)c * HID + h;
        cH0[o] = carry;
        carry = cA[o] * carry + cB[o];
    }
}

// scan pass3 (one batch): replay with carry-in, write h
__global__ __launch_bounds__(256) void scan3_kernel(const float* __restrict__ alpha,
                                                    const float* __restrict__ xh2,
                                                    const double* __restrict__ cH0,
                                                    float* __restrict__ hout)
{
    int idx = blockIdx.x * 256 + threadIdx.x;
    if (idx >= NCH * HID) return;
    int h = idx % HID;
    int c = idx / HID;
    size_t base = (size_t)c * CHL * HID + h;
    double hv = cH0[(size_t)c * HID + h];
    for (int i = 0; i < CHL; i++) {
        double a  = (double)alpha[base + (size_t)i * HID];
        double xv = (double)xh2 [base + (size_t)i * HID];
        hv = a * hv + xv;
        hout[base + (size_t)i * HID] = (float)hv;
    }
}

// xr = gelu_exact(xh3)*h, in-place over xh3
__global__ __launch_bounds__(256) void gelu_mul_kernel(float* __restrict__ xh3,
                                                       const float* __restrict__ hbuf)
{
    size_t i = (size_t)blockIdx.x * 256 + threadIdx.x;
    if (i >= TH) return;
    double x3 = (double)xh3[i];
    double ge = 0.5 * x3 * (1.0 + erf(x3 * 0.70710678118654752440));
    xh3[i] = (float)(ge * (double)hbuf[i]);
}

// attention 1 (one batch): per segment s, softmax over l=256, mem[s,:] = sum attn*v
// kv is [T][2*DD]: cols [0,DD) = k, [DD,2DD) = v
__global__ __launch_bounds__(256) void attn1_kernel(const float* __restrict__ kv,
                                                    const float* __restrict__ qbuf,
                                                    float* __restrict__ mem)
{
    const int s = blockIdx.x;
    const int l = threadIdx.x;
    const size_t row = (size_t)s * LSEG + l;
    const float* kr = kv + row * (2 * DD);
    const float* qs = qbuf + (size_t)s * DD;
    double acc = 0.0;
    for (int d = 0; d < DD; d++) acc += (double)qs[d] * (double)kr[d];
    double qk = acc / sqrt((double)DD);
    __shared__ double r1[256];
    __shared__ double sw[256];
    r1[l] = qk; __syncthreads();
    for (int off = 128; off > 0; off >>= 1) {
        if (l < off) r1[l] = fmax(r1[l], r1[l + off]);
        __syncthreads();
    }
    double m = r1[0]; __syncthreads();
    double e = exp(qk - m);
    r1[l] = e; __syncthreads();
    for (int off = 128; off > 0; off >>= 1) {
        if (l < off) r1[l] += r1[l + off];
        __syncthreads();
    }
    double denom = r1[0];
    sw[l] = e / denom; __syncthreads();
    const size_t vbase = (size_t)s * LSEG * (2 * DD) + DD;
    for (int d = l; d < DD; d += 256) {
        double a2 = 0.0;
        for (int ll = 0; ll < LSEG; ll++)
            a2 += sw[ll] * (double)kv[vbase + (size_t)ll * (2 * DD) + d];
        mem[(size_t)s * DD + d] = (float)a2;
    }
}

// attention 2 + output gate (one batch): one block per token
__global__ __launch_bounds__(256) void attn2_kernel(const float* __restrict__ rq,
                                                    const float* __restrict__ rk,
                                                    const float* __restrict__ rv,
                                                    const float* __restrict__ xr,
                                                    const float* __restrict__ wg,
                                                    float* __restrict__ out2)
{
    const int t = blockIdx.x;
    const int sigma = t >> 8;          // t / LSEG
    const int tid = threadIdx.x;
    __shared__ double sqk[16];
    __shared__ double red[256];
    __shared__ double sw[16];
    __shared__ double sgate;

    const float* rqn = rq + (size_t)t * DD;
    {
        int s = tid >> 4, j = tid & 15;
        const float* rks = rk + (size_t)s * DD;
        double part = 0.0;
        for (int d = j; d < DD; d += 16) part += (double)rqn[d] * (double)rks[d];
#pragma unroll
        for (int off = 8; off > 0; off >>= 1) part += __shfl_down(part, off, 16);
        if (j == 0) sqk[s] = part;
    }
    double gp = 0.0;
    const float* xrn = xr + (size_t)t * HID;
    for (int hh = tid; hh < HID; hh += 256) gp += (double)xrn[hh] * (double)wg[hh];
    red[tid] = gp; __syncthreads();
    for (int off = 128; off > 0; off >>= 1) {
        if (tid < off) red[tid] += red[tid + off];
        __syncthreads();
    }
    if (tid == 0) {
        const double inv = 1.0 / sqrt((double)DD);
        double m = -1e300;
        for (int ss = sigma; ss < 16; ss++) {
            double v = sqk[ss] * inv;
            sqk[ss] = v;
            if (v > m) m = v;
        }
        double sum = 0.0;
        for (int ss = sigma; ss < 16; ss++) {
            double e = exp(sqk[ss] - m);
            sw[ss] = e;
            sum += e;
        }
        double isum = 1.0 / sum;
        for (int ss = 0; ss < sigma; ss++) sw[ss] = 0.0;
        for (int ss = sigma; ss < 16; ss++) sw[ss] *= isum;
        sgate = 1.0 / (1.0 + exp(-red[0]));
    }
    __syncthreads();
    const double gte = sgate;
    for (int hh = tid; hh < HID; hh += 256) {
        double acc = 0.0;
        for (int ss = sigma; ss < 16; ss++) acc += sw[ss] * (double)rv[(size_t)ss * HID + hh];
        out2[(size_t)t * HID + hh] = (float)(gte * acc);
    }
}

extern "C" void kernel_launch(void* const* d_in, const int* in_sizes, int n_in,
                              void* d_out, int out_size, void* d_ws, size_t ws_size,
                              hipStream_t stream)
{
    const float* x            = (const float*)d_in[0];
    const float* input_w      = (const float*)d_in[1];
    const float* conv_w       = (const float*)d_in[2];
    const float* conv_b       = (const float*)d_in[3];
    const float* gates_w      = (const float*)d_in[4];
    const float* gates_b      = (const float*)d_in[5];
    const float* forget_base  = (const float*)d_in[6];
    const float* output_w     = (const float*)d_in[7];
    const float* memory_slots = (const float*)d_in[8];
    const float* wq_w         = (const float*)d_in[9];
    const float* wk_w         = (const float*)d_in[10];
    const float* wv_w         = (const float*)d_in[11];
    const float* wg_w         = (const float*)d_in[12];
    const float* rq_w         = (const float*)d_in[13];
    const float* rk_w         = (const float*)d_in[14];
    const float* rv_w         = (const float*)d_in[15];
    float* out = (float*)d_out;

    // workspace layout: doubles first (8B align), then fp32 slots. ~83 MB total.
    double* spb  = (double*)d_ws;                     // HID
    double* cA   = spb + HID;                         // NCH*HID
    double* cB   = cA + (size_t)NCH * HID;
    double* cH0  = cB + (size_t)NCH * HID;
    float* slotA = (float*)(cH0 + (size_t)NCH * HID); // TH floats each
    float* slotB = slotA + TH;
    float* slotC = slotB + TH;
    float* qbuf   = slotC + TH;                       // 16*384
    float* membuf = qbuf + (size_t)SSEG * DD;         // 16*384
    float* rkbuf  = membuf + (size_t)SSEG * DD;       // 16*384
    float* rvbuf  = rkbuf + (size_t)SSEG * DD;        // 16*1536
    float* wkv    = rvbuf + (size_t)SSEG * HID;       // 768*1536

    dim3 blk(256);
    const int ewBlocks = (int)(TH / 256);             // 24576

    // once: softplus(forget_base); wkv concat; q = memory_slots @ wq_w.T
    spb_kernel<<<(HID + 255) / 256, blk, 0, stream>>>(forget_base, spb);
    catkv_kernel<<<(2 * DD * HID) / 256, blk, 0, stream>>>(wk_w, wv_w, wkv);
    gemm32<0, 64, 64><<<dim3(1, DD / 64), blk, 0, stream>>>(
        memory_slots, wq_w, qbuf, (float*)nullptr, (const float*)nullptr, SSEG, DD, DD);

    for (int b = 0; b < BB; b++) {
        const float* xb   = x   + (size_t)b * TT * DIMW;
        float*       outb = out + (size_t)b * TT * DIMW;

        // xh0 = xb @ input_w[HID:,:].T  -> slotB
        gemm32<0, 128, 128><<<dim3(TT / 128, HID / 128), blk, 0, stream>>>(
            xb, input_w + (size_t)HID * DIMW, slotB, (float*)nullptr,
            (const float*)nullptr, TT, HID, DIMW);
        // xh1 = causal conv(xh0) -> slotC
        conv_kernel<<<ewBlocks, blk, 0, stream>>>(slotB, conv_w, conv_b, slotC);
        // g = xh1 @ gates_w.T -> forget(slotA), inp(slotB)  (bias later)
        gemm32<1, 128, 128><<<dim3(TT / 128, HID2 / 128), blk, 0, stream>>>(
            slotC, gates_w, slotA, slotB, (const float*)nullptr, TT, HID2, HID);
        // alpha(slotA), xh2(slotB) in-place, reads xh1(slotC)
        alpha_xh2_kernel<<<ewBlocks, blk, 0, stream>>>(slotA, slotB, slotC, spb, gates_b);
        // scan -> h(slotC)
        scan1_kernel<<<(NCH * HID) / 256, blk, 0, stream>>>(slotA, slotB, cA, cB);
        scan2_kernel<<<(HID + 255) / 256, blk, 0, stream>>>(cA, cB, cH0);
        scan3_kernel<<<(NCH * HID) / 256, blk, 0, stream>>>(slotA, slotB, cH0, slotC);
        // xh3 = silu(xb @ input_w[:HID].T) * xh2(slotB) -> slotA
        gemm32<2, 128, 128><<<dim3(TT / 128, HID / 128), blk, 0, stream>>>(
            xb, input_w, slotA, (float*)nullptr, slotB, TT, HID, DIMW);
        // k|v projections in one GEMM -> slotB [T][768] (xh2 dead)
        gemm32<0, 128, 64><<<dim3(TT / 128, (2 * DD) / 64), blk, 0, stream>>>(
            slotA, wkv, slotB, (float*)nullptr, (const float*)nullptr, TT, 2 * DD, HID);
        // segment attention -> membuf
        attn1_kernel<<<SSEG, blk, 0, stream>>>(slotB, qbuf, membuf);
        // xr = gelu(xh3)*h -> slotA in-place (reads slotC)
        gelu_mul_kernel<<<ewBlocks, blk, 0, stream>>>(slotA, slotC);
        // rq = xr @ rq_w.T -> slotB (kv dead)
        gemm32<0, 64, 64><<<dim3(TT / 64, DD / 64), blk, 0, stream>>>(
            slotA, rq_w, slotB, (float*)nullptr, (const float*)nullptr, TT, DD, HID);
        // rk = mem @ rk_w.T ; rv = mem @ rv_w.T
        gemm32<0, 64, 64><<<dim3(1, DD / 64), blk, 0, stream>>>(
            membuf, rk_w, rkbuf, (float*)nullptr, (const float*)nullptr, SSEG, DD, DD);
        gemm32<0, 64, 64><<<dim3(1, HID / 64), blk, 0, stream>>>(
            membuf, rv_w, rvbuf, (float*)nullptr, (const float*)nullptr, SSEG, HID, DD);
        // cross attention + gate -> out2(slotC) (h dead)
        attn2_kernel<<<TT, blk, 0, stream>>>(slotB, rkbuf, rvbuf, slotA, wg_w, slotC);
        // final projection -> d_out (fp32)
        gemm32<0, 128, 128><<<dim3(TT / 128, DIMW / 128), blk, 0, stream>>>(
            slotC, output_w, outb, (float*)nullptr, (const float*)nullptr, TT, DIMW, HID);
    }
}

// Round 2
// 3849.868 us; speedup vs baseline: 3.4724x; 2.1931x over previous
//
#include <hip/hip_runtime.h>
#include <math.h>

#define BB 4
#define TT 4096
#define DIMW 1024
#define HID 1536
#define HID2 3072
#define KC 4
#define SSEG 16
#define LSEG 256
#define DD 384
#define NCH 64          // scan chunks per batch
#define CHL 64          // tokens per chunk (NCH*CHL == TT)
#define TH  ((size_t)TT*(size_t)HID)   // elements in one T x HID slot

typedef __bf16 bf8 __attribute__((ext_vector_type(8)));
typedef float f4 __attribute__((ext_vector_type(4)));
typedef unsigned short us8 __attribute__((ext_vector_type(8)));

__device__ __forceinline__ unsigned short f2bf(float f) {
    unsigned u = __builtin_bit_cast(unsigned, f);
    u += 0x7fffu + ((u >> 16) & 1u);
    return (unsigned short)(u >> 16);
}
__device__ __forceinline__ float bf2f(unsigned short h) {
    unsigned u = ((unsigned)h) << 16;
    return __builtin_bit_cast(float, u);
}

// =====================================================================
// Split-bf16 MFMA GEMM: C[m,n] = sum_k A[m,k] * W[n,k]
// A: fp32, split on the fly into 3 bf16 planes during LDS staging.
// W: pre-split 3 bf16 planes (plane stride wps elems), row-major [N][K].
// 6-product scheme (a0b0,a0b1,a1b0,a0b2,a1b1,a2b0): fp32-equivalent
// accuracy, fp32 MFMA accumulation. Tile 128x128, BK=32, 4 waves (2x2),
// each wave 64x64 = 4x4 fragments of mfma_f32_16x16x32_bf16.
// LDS layout [plane][kc][row(129 pad)][8] -> frag reads & staging writes
// are <=2 lanes/bank (free). Register-prefetch double buffering.
// MODE 0: plain fp32 store; MODE 1: split cols at HID -> C0/C1;
// MODE 2: C0 = silu(acc) * X
// =====================================================================
#define LIDX(kc,row) ((((kc) * 129) + (row)) * 8)

template<int MODE>
__global__ __launch_bounds__(256) void gemm_mfma(const float* __restrict__ A,
                                                 const unsigned short* __restrict__ Wp,
                                                 size_t wps,
                                                 float* __restrict__ C0,
                                                 float* __restrict__ C1,
                                                 const float* __restrict__ X,
                                                 int M, int Nout, int Kd)
{
    __shared__ unsigned short Als[3][4 * 129 * 8];
    __shared__ unsigned short Bls[3][4 * 129 * 8];
    const int tid = threadIdx.x;
    const int lane = tid & 63;
    const int wv = tid >> 6;
    const int wr = wv >> 1, wc = wv & 1;
    const int lr = lane & 15, lg = lane >> 4;
    const int m0 = blockIdx.x * 128, n0 = blockIdx.y * 128;

    const int srow = tid >> 2;       // 0..63
    const int skc  = tid & 3;        // 0..3

    f4 acc[4][4];
#pragma unroll
    for (int i = 0; i < 4; i++)
#pragma unroll
        for (int j = 0; j < 4; j++) acc[i][j] = (f4){0.f, 0.f, 0.f, 0.f};

    float4 aR[4];
    us8 wR[2][3];

    const float* Ab0 = A + (size_t)(m0 + srow) * Kd + skc * 8;
    const float* Ab1 = Ab0 + (size_t)64 * Kd;
    const unsigned short* Wb0 = Wp + (size_t)(n0 + srow) * Kd + skc * 8;
    const unsigned short* Wb1 = Wb0 + (size_t)64 * Kd;

    auto loadG = [&](int k0) {
        aR[0] = *(const float4*)(Ab0 + k0);
        aR[1] = *(const float4*)(Ab0 + k0 + 4);
        aR[2] = *(const float4*)(Ab1 + k0);
        aR[3] = *(const float4*)(Ab1 + k0 + 4);
#pragma unroll
        for (int pl = 0; pl < 3; pl++) {
            wR[0][pl] = *(const us8*)(Wb0 + pl * wps + k0);
            wR[1][pl] = *(const us8*)(Wb1 + pl * wps + k0);
        }
    };
    auto writeL = [&]() {
#pragma unroll
        for (int u = 0; u < 2; u++) {
            const int row = srow + u * 64;
            float f[8];
            f[0] = aR[2*u].x; f[1] = aR[2*u].y; f[2] = aR[2*u].z; f[3] = aR[2*u].w;
            f[4] = aR[2*u+1].x; f[5] = aR[2*u+1].y; f[6] = aR[2*u+1].z; f[7] = aR[2*u+1].w;
            us8 h0, h1, h2;
#pragma unroll
            for (int e = 0; e < 8; e++) {
                float a = f[e];
                unsigned short s0 = f2bf(a);
                float r = a - bf2f(s0);
                unsigned short s1 = f2bf(r);
                unsigned short s2 = f2bf(r - bf2f(s1));
                h0[e] = s0; h1[e] = s1; h2[e] = s2;
            }
            *(us8*)&Als[0][LIDX(skc, row)] = h0;
            *(us8*)&Als[1][LIDX(skc, row)] = h1;
            *(us8*)&Als[2][LIDX(skc, row)] = h2;
#pragma unroll
            for (int pl = 0; pl < 3; pl++)
                *(us8*)&Bls[pl][LIDX(skc, row)] = wR[u][pl];
        }
    };

    loadG(0);
    writeL();
    __syncthreads();

    const int NS = Kd / 32;
    for (int t = 0; t < NS; t++) {
        if (t + 1 < NS) loadG((t + 1) * 32);

        bf8 af[4][3];
#pragma unroll
        for (int mi = 0; mi < 4; mi++) {
            const int row = wr * 64 + mi * 16 + lr;
#pragma unroll
            for (int pl = 0; pl < 3; pl++)
                af[mi][pl] = __builtin_bit_cast(bf8, *(const us8*)&Als[pl][LIDX(lg, row)]);
        }
#pragma unroll
        for (int ni = 0; ni < 4; ni++) {
            const int row = wc * 64 + ni * 16 + lr;
            bf8 b0 = __builtin_bit_cast(bf8, *(const us8*)&Bls[0][LIDX(lg, row)]);
            bf8 b1 = __builtin_bit_cast(bf8, *(const us8*)&Bls[1][LIDX(lg, row)]);
            bf8 b2 = __builtin_bit_cast(bf8, *(const us8*)&Bls[2][LIDX(lg, row)]);
#pragma unroll
            for (int mi = 0; mi < 4; mi++) {
                f4 d = acc[mi][ni];
                d = __builtin_amdgcn_mfma_f32_16x16x32_bf16(af[mi][0], b0, d, 0, 0, 0);
                d = __builtin_amdgcn_mfma_f32_16x16x32_bf16(af[mi][0], b1, d, 0, 0, 0);
                d = __builtin_amdgcn_mfma_f32_16x16x32_bf16(af[mi][1], b0, d, 0, 0, 0);
                d = __builtin_amdgcn_mfma_f32_16x16x32_bf16(af[mi][0], b2, d, 0, 0, 0);
                d = __builtin_amdgcn_mfma_f32_16x16x32_bf16(af[mi][1], b1, d, 0, 0, 0);
                d = __builtin_amdgcn_mfma_f32_16x16x32_bf16(af[mi][2], b0, d, 0, 0, 0);
                acc[mi][ni] = d;
            }
        }
        __syncthreads();
        if (t + 1 < NS) {
            writeL();
            __syncthreads();
        }
    }

#pragma unroll
    for (int mi = 0; mi < 4; mi++) {
#pragma unroll
        for (int ni = 0; ni < 4; ni++) {
            f4 v = acc[mi][ni];
#pragma unroll
            for (int r = 0; r < 4; r++) {
                const int m = m0 + wr * 64 + mi * 16 + lg * 4 + r;
                const int n = n0 + wc * 64 + ni * 16 + lr;
                if constexpr (MODE == 1) {
                    if (n < HID) C0[(size_t)m * HID + n] = v[r];
                    else         C1[(size_t)m * HID + (n - HID)] = v[r];
                } else if constexpr (MODE == 2) {
                    double g = (double)v[r];
                    double val = (g / (1.0 + exp(-g))) * (double)X[(size_t)m * Nout + n];
                    C0[(size_t)m * Nout + n] = (float)val;
                } else {
                    C0[(size_t)m * Nout + n] = v[r];
                }
            }
        }
    }
}

// split fp32 weights into 3 bf16 planes (once)
__global__ __launch_bounds__(256) void wsplit_kernel(const float* __restrict__ src,
                                                     unsigned short* __restrict__ dst,
                                                     size_t n, size_t planeStride)
{
    size_t i = (size_t)blockIdx.x * 256 + threadIdx.x;
    if (i >= n) return;
    float a = src[i];
    unsigned short s0 = f2bf(a);
    float r = a - bf2f(s0);
    unsigned short s1 = f2bf(r);
    unsigned short s2 = f2bf(r - bf2f(s1));
    dst[i] = s0;
    dst[planeStride + i] = s1;
    dst[2 * planeStride + i] = s2;
}

// =====================================================================
// fp32 VALU GEMM kept only for tiny M=16 matmuls (q, rk, rv)
// =====================================================================
template<int MODE, int TM, int TN>
__global__ __launch_bounds__(256) void gemm32(const float* __restrict__ A,
                                              const float* __restrict__ W,
                                              float* __restrict__ C0,
                                              float* __restrict__ C1,
                                              const float* __restrict__ X,
                                              int M, int Nout, int Kd)
{
    constexpr int GM = TM / 64;
    constexpr int GN = TN / 64;
    constexpr int AF4 = TM * 4;
    constexpr int WF4 = TN * 4;
    constexpr int ALOOP = (AF4 + 255) / 256;
    constexpr int WLOOP = (WF4 + 255) / 256;

    __shared__ float As[16][TM];
    __shared__ float Bs[16][TN];

    const int tid = threadIdx.x;
    const int m0 = blockIdx.x * TM;
    const int n0 = blockIdx.y * TN;
    const int tx = tid & 15, ty = tid >> 4;

    float acc[GM * 4][GN * 4];
#pragma unroll
    for (int i = 0; i < GM * 4; i++)
#pragma unroll
        for (int j = 0; j < GN * 4; j++) acc[i][j] = 0.0f;

    float4 aReg[ALOOP], wReg[WLOOP];

    auto issueLoads = [&](int k0) {
#pragma unroll
        for (int u = 0; u < ALOOP; u++) {
            const int idx = tid + u * 256;
            float4 v = make_float4(0.f, 0.f, 0.f, 0.f);
            if (idx < AF4) {
                const int row = idx >> 2, kq = (idx & 3) * 4;
                const long ar = (long)(m0 + row);
                if (ar < M) v = *(const float4*)(A + ar * (long)Kd + (k0 + kq));
            }
            aReg[u] = v;
        }
#pragma unroll
        for (int u = 0; u < WLOOP; u++) {
            const int idx = tid + u * 256;
            float4 v = make_float4(0.f, 0.f, 0.f, 0.f);
            if (idx < WF4) {
                const int row = idx >> 2, kq = (idx & 3) * 4;
                const long wr = (long)(n0 + row);
                v = *(const float4*)(W + wr * (long)Kd + (k0 + kq));
            }
            wReg[u] = v;
        }
    };
    auto writeLDS = [&]() {
#pragma unroll
        for (int u = 0; u < ALOOP; u++) {
            const int idx = tid + u * 256;
            if (idx < AF4) {
                const int row = idx >> 2, kq = (idx & 3) * 4;
                As[kq + 0][row] = aReg[u].x;
                As[kq + 1][row] = aReg[u].y;
                As[kq + 2][row] = aReg[u].z;
                As[kq + 3][row] = aReg[u].w;
            }
        }
#pragma unroll
        for (int u = 0; u < WLOOP; u++) {
            const int idx = tid + u * 256;
            if (idx < WF4) {
                const int row = idx >> 2, kq = (idx & 3) * 4;
                Bs[kq + 0][row] = wReg[u].x;
                Bs[kq + 1][row] = wReg[u].y;
                Bs[kq + 2][row] = wReg[u].z;
                Bs[kq + 3][row] = wReg[u].w;
            }
        }
    };

    issueLoads(0);
    writeLDS();
    __syncthreads();

    const int NT = Kd / 16;
    for (int t = 0; t < NT; t++) {
        if (t + 1 < NT) issueLoads((t + 1) * 16);
#pragma unroll
        for (int k = 0; k < 16; k++) {
            float a[GM * 4], b[GN * 4];
#pragma unroll
            for (int g = 0; g < GM; g++) {
                const float4 t4 = *(const float4*)&As[k][g * 64 + ty * 4];
                a[g * 4 + 0] = t4.x; a[g * 4 + 1] = t4.y;
                a[g * 4 + 2] = t4.z; a[g * 4 + 3] = t4.w;
            }
#pragma unroll
            for (int g = 0; g < GN; g++) {
                const float4 t4 = *(const float4*)&Bs[k][g * 64 + tx * 4];
                b[g * 4 + 0] = t4.x; b[g * 4 + 1] = t4.y;
                b[g * 4 + 2] = t4.z; b[g * 4 + 3] = t4.w;
            }
#pragma unroll
            for (int i = 0; i < GM * 4; i++)
#pragma unroll
                for (int j = 0; j < GN * 4; j++) acc[i][j] += a[i] * b[j];
        }
        __syncthreads();
        if (t + 1 < NT) {
            writeLDS();
            __syncthreads();
        }
    }

#pragma unroll
    for (int i = 0; i < GM * 4; i++) {
        const int m = m0 + (i >> 2) * 64 + ty * 4 + (i & 3);
        if (m >= M) continue;
#pragma unroll
        for (int j = 0; j < GN * 4; j++) {
            const int n = n0 + (j >> 2) * 64 + tx * 4 + (j & 3);
            if (n >= Nout) continue;
            C0[(long)m * Nout + n] = acc[i][j];
        }
    }
}

// softplus(forget_base) per channel (once)
__global__ __launch_bounds__(256) void spb_kernel(const float* __restrict__ fb,
                                                  double* __restrict__ spb)
{
    int h = blockIdx.x * 256 + threadIdx.x;
    if (h < HID) {
        double xv = (double)fb[h];
        spb[h] = log1p(exp(xv));
    }
}

// causal depthwise conv (one batch)
__global__ __launch_bounds__(256) void conv_kernel(const float* __restrict__ xin,
                                                   const float* __restrict__ cw,
                                                   const float* __restrict__ cb,
                                                   float* __restrict__ outp)
{
    size_t i = (size_t)blockIdx.x * 256 + threadIdx.x;
    if (i >= TH) return;
    int h = (int)(i % HID);
    int t = (int)(i / HID);
    double acc = (double)cb[h];
#pragma unroll
    for (int j = 0; j < KC; j++) {
        int tt = t - (KC - 1) + j;
        if (tt >= 0) acc += (double)cw[h * KC + j] * (double)xin[(size_t)tt * HID + h];
    }
    outp[i] = (float)acc;
}

// raw forget(fg)/inp(ip) (+bias) -> alpha, xh2 : in-place, reads xh1
__global__ __launch_bounds__(256) void alpha_xh2_kernel(float* __restrict__ fg,
                                                        float* __restrict__ ip,
                                                        const float* __restrict__ xh1,
                                                        const double* __restrict__ spb,
                                                        const float* __restrict__ gb)
{
    size_t i = (size_t)blockIdx.x * 256 + threadIdx.x;
    if (i >= TH) return;
    int h = (int)(i % HID);
    double f  = (double)fg[i] + (double)gb[h];
    double g2 = (double)ip[i] + (double)gb[HID + h];
    double sigf = 1.0 / (1.0 + exp(-f));
    double alpha = exp(-8.0 * spb[h] * sigf);
    double s2 = sqrt(1.0 - alpha * alpha + 1e-6);
    double sigi = 1.0 / (1.0 + exp(-g2));
    double x1 = (double)xh1[i];
    fg[i] = (float)alpha;
    ip[i] = (float)(s2 * sigi * x1);
}

// scan pass1
__global__ __launch_bounds__(256) void scan1_kernel(const float* __restrict__ alpha,
                                                    const float* __restrict__ xh2,
                                                    double* __restrict__ cA,
                                                    double* __restrict__ cB)
{
    int idx = blockIdx.x * 256 + threadIdx.x;
    if (idx >= NCH * HID) return;
    int h = idx % HID;
    int c = idx / HID;
    size_t base = (size_t)c * CHL * HID + h;
    double aP = 1.0, bV = 0.0;
    for (int i = 0; i < CHL; i++) {
        double a  = (double)alpha[base + (size_t)i * HID];
        double xv = (double)xh2 [base + (size_t)i * HID];
        bV = a * bV + xv;
        aP *= a;
    }
    size_t o = (size_t)c * HID + h;
    cA[o] = aP;
    cB[o] = bV;
}

// scan pass2
__global__ __launch_bounds__(256) void scan2_kernel(const double* __restrict__ cA,
                                                    const double* __restrict__ cB,
                                                    double* __restrict__ cH0)
{
    int h = blockIdx.x * 256 + threadIdx.x;
    if (h >= HID) return;
    double carry = 0.0;
    for (int c = 0; c < NCH; c++) {
        size_t o = (size_t)c * HID + h;
        cH0[o] = carry;
        carry = cA[o] * carry + cB[o];
    }
}

// scan pass3
__global__ __launch_bounds__(256) void scan3_kernel(const float* __restrict__ alpha,
                                                    const float* __restrict__ xh2,
                                                    const double* __restrict__ cH0,
                                                    float* __restrict__ hout)
{
    int idx = blockIdx.x * 256 + threadIdx.x;
    if (idx >= NCH * HID) return;
    int h = idx % HID;
    int c = idx / HID;
    size_t base = (size_t)c * CHL * HID + h;
    double hv = cH0[(size_t)c * HID + h];
    for (int i = 0; i < CHL; i++) {
        double a  = (double)alpha[base + (size_t)i * HID];
        double xv = (double)xh2 [base + (size_t)i * HID];
        hv = a * hv + xv;
        hout[base + (size_t)i * HID] = (float)hv;
    }
}

// xr = gelu_exact(xh3)*h, in-place over xh3
__global__ __launch_bounds__(256) void gelu_mul_kernel(float* __restrict__ xh3,
                                                       const float* __restrict__ hbuf)
{
    size_t i = (size_t)blockIdx.x * 256 + threadIdx.x;
    if (i >= TH) return;
    double x3 = (double)xh3[i];
    double ge = 0.5 * x3 * (1.0 + erf(x3 * 0.70710678118654752440));
    xh3[i] = (float)(ge * (double)hbuf[i]);
}

// attention 1: kv is [T][2*DD], cols [0,DD)=k, [DD,2DD)=v
__global__ __launch_bounds__(256) void attn1_kernel(const float* __restrict__ kv,
                                                    const float* __restrict__ qbuf,
                                                    float* __restrict__ mem)
{
    const int s = blockIdx.x;
    const int l = threadIdx.x;
    const size_t row = (size_t)s * LSEG + l;
    const float* kr = kv + row * (2 * DD);
    const float* qs = qbuf + (size_t)s * DD;
    double acc = 0.0;
    for (int d = 0; d < DD; d++) acc += (double)qs[d] * (double)kr[d];
    double qk = acc / sqrt((double)DD);
    __shared__ double r1[256];
    __shared__ double sw[256];
    r1[l] = qk; __syncthreads();
    for (int off = 128; off > 0; off >>= 1) {
        if (l < off) r1[l] = fmax(r1[l], r1[l + off]);
        __syncthreads();
    }
    double m = r1[0]; __syncthreads();
    double e = exp(qk - m);
    r1[l] = e; __syncthreads();
    for (int off = 128; off > 0; off >>= 1) {
        if (l < off) r1[l] += r1[l + off];
        __syncthreads();
    }
    double denom = r1[0];
    sw[l] = e / denom; __syncthreads();
    const size_t vbase = (size_t)s * LSEG * (2 * DD) + DD;
    for (int d = l; d < DD; d += 256) {
        double a2 = 0.0;
        for (int ll = 0; ll < LSEG; ll++)
            a2 += sw[ll] * (double)kv[vbase + (size_t)ll * (2 * DD) + d];
        mem[(size_t)s * DD + d] = (float)a2;
    }
}

// attention 2 + output gate
__global__ __launch_bounds__(256) void attn2_kernel(const float* __restrict__ rq,
                                                    const float* __restrict__ rk,
                                                    const float* __restrict__ rv,
                                                    const float* __restrict__ xr,
                                                    const float* __restrict__ wg,
                                                    float* __restrict__ out2)
{
    const int t = blockIdx.x;
    const int sigma = t >> 8;
    const int tid = threadIdx.x;
    __shared__ double sqk[16];
    __shared__ double red[256];
    __shared__ double sw[16];
    __shared__ double sgate;

    const float* rqn = rq + (size_t)t * DD;
    {
        int s = tid >> 4, j = tid & 15;
        const float* rks = rk + (size_t)s * DD;
        double part = 0.0;
        for (int d = j; d < DD; d += 16) part += (double)rqn[d] * (double)rks[d];
#pragma unroll
        for (int off = 8; off > 0; off >>= 1) part += __shfl_down(part, off, 16);
        if (j == 0) sqk[s] = part;
    }
    double gp = 0.0;
    const float* xrn = xr + (size_t)t * HID;
    for (int hh = tid; hh < HID; hh += 256) gp += (double)xrn[hh] * (double)wg[hh];
    red[tid] = gp; __syncthreads();
    for (int off = 128; off > 0; off >>= 1) {
        if (tid < off) red[tid] += red[tid + off];
        __syncthreads();
    }
    if (tid == 0) {
        const double inv = 1.0 / sqrt((double)DD);
        double m = -1e300;
        for (int ss = sigma; ss < 16; ss++) {
            double v = sqk[ss] * inv;
            sqk[ss] = v;
            if (v > m) m = v;
        }
        double sum = 0.0;
        for (int ss = sigma; ss < 16; ss++) {
            double e = exp(sqk[ss] - m);
            sw[ss] = e;
            sum += e;
        }
        double isum = 1.0 / sum;
        for (int ss = 0; ss < sigma; ss++) sw[ss] = 0.0;
        for (int ss = sigma; ss < 16; ss++) sw[ss] *= isum;
        sgate = 1.0 / (1.0 + exp(-red[0]));
    }
    __syncthreads();
    const double gte = sgate;
    for (int hh = tid; hh < HID; hh += 256) {
        double acc = 0.0;
        for (int ss = sigma; ss < 16; ss++) acc += sw[ss] * (double)rv[(size_t)ss * HID + hh];
        out2[(size_t)t * HID + hh] = (float)(gte * acc);
    }
}

extern "C" void kernel_launch(void* const* d_in, const int* in_sizes, int n_in,
                              void* d_out, int out_size, void* d_ws, size_t ws_size,
                              hipStream_t stream)
{
    const float* x            = (const float*)d_in[0];
    const float* input_w      = (const float*)d_in[1];
    const float* conv_w       = (const float*)d_in[2];
    const float* conv_b       = (const float*)d_in[3];
    const float* gates_w      = (const float*)d_in[4];
    const float* gates_b      = (const float*)d_in[5];
    const float* forget_base  = (const float*)d_in[6];
    const float* output_w     = (const float*)d_in[7];
    const float* memory_slots = (const float*)d_in[8];
    const float* wq_w         = (const float*)d_in[9];
    const float* wk_w         = (const float*)d_in[10];
    const float* wv_w         = (const float*)d_in[11];
    const float* wg_w         = (const float*)d_in[12];
    const float* rq_w         = (const float*)d_in[13];
    const float* rk_w         = (const float*)d_in[14];
    const float* rv_w         = (const float*)d_in[15];
    float* out = (float*)d_out;

    // workspace: doubles | 3 fp32 slots | small fp32 | bf16 weight planes (~145MB)
    double* spb  = (double*)d_ws;                     // HID
    double* cA   = spb + HID;                         // NCH*HID
    double* cB   = cA + (size_t)NCH * HID;
    double* cH0  = cB + (size_t)NCH * HID;
    float* slotA = (float*)(cH0 + (size_t)NCH * HID);
    float* slotB = slotA + TH;
    float* slotC = slotB + TH;
    float* qbuf   = slotC + TH;                       // 16*384
    float* membuf = qbuf + (size_t)SSEG * DD;
    float* rkbuf  = membuf + (size_t)SSEG * DD;
    float* rvbuf  = rkbuf + (size_t)SSEG * DD;        // 16*1536
    unsigned short* iwp  = (unsigned short*)(rvbuf + (size_t)SSEG * HID);
    const size_t iwN  = (size_t)HID2 * DIMW;          // 3.1M
    unsigned short* gwp  = iwp + 3 * iwN;
    const size_t gwN  = (size_t)HID2 * HID;           // 4.7M
    unsigned short* wkvp = gwp + 3 * gwN;
    const size_t kvN  = (size_t)(2 * DD) * HID;       // 1.18M
    unsigned short* rqwp = wkvp + 3 * kvN;
    const size_t rqN  = (size_t)DD * HID;             // 0.59M
    unsigned short* owp  = rqwp + 3 * rqN;
    const size_t owN  = (size_t)DIMW * HID;           // 1.57M

    dim3 blk(256);
    const int ewBlocks = (int)(TH / 256);

    // one-time: softplus, weight splits, q projection
    spb_kernel<<<(HID + 255) / 256, blk, 0, stream>>>(forget_base, spb);
    wsplit_kernel<<<(int)((iwN + 255) / 256), blk, 0, stream>>>(input_w, iwp, iwN, iwN);
    wsplit_kernel<<<(int)((gwN + 255) / 256), blk, 0, stream>>>(gates_w, gwp, gwN, gwN);
    wsplit_kernel<<<(int)((rqN + 255) / 256), blk, 0, stream>>>(wk_w, wkvp, rqN, kvN);
    wsplit_kernel<<<(int)((rqN + 255) / 256), blk, 0, stream>>>(wv_w, wkvp + rqN, rqN, kvN);
    wsplit_kernel<<<(int)((rqN + 255) / 256), blk, 0, stream>>>(rq_w, rqwp, rqN, rqN);
    wsplit_kernel<<<(int)((owN + 255) / 256), blk, 0, stream>>>(output_w, owp, owN, owN);
    gemm32<0, 64, 64><<<dim3(1, DD / 64), blk, 0, stream>>>(
        memory_slots, wq_w, qbuf, (float*)nullptr, (const float*)nullptr, SSEG, DD, DD);

    for (int b = 0; b < BB; b++) {
        const float* xb   = x   + (size_t)b * TT * DIMW;
        float*       outb = out + (size_t)b * TT * DIMW;

        // xh0 = xb @ input_w[HID:,:].T -> slotB
        gemm_mfma<0><<<dim3(TT / 128, HID / 128), blk, 0, stream>>>(
            xb, iwp + (size_t)HID * DIMW, iwN, slotB, (float*)nullptr,
            (const float*)nullptr, TT, HID, DIMW);
        // xh1 = causal conv(xh0) -> slotC
        conv_kernel<<<ewBlocks, blk, 0, stream>>>(slotB, conv_w, conv_b, slotC);
        // g = xh1 @ gates_w.T -> forget(slotA), inp(slotB)
        gemm_mfma<1><<<dim3(TT / 128, HID2 / 128), blk, 0, stream>>>(
            slotC, gwp, gwN, slotA, slotB, (const float*)nullptr, TT, HID2, HID);
        // alpha(slotA), xh2(slotB) in-place, reads xh1(slotC)
        alpha_xh2_kernel<<<ewBlocks, blk, 0, stream>>>(slotA, slotB, slotC, spb, gates_b);
        // scan -> h(slotC)
        scan1_kernel<<<(NCH * HID) / 256, blk, 0, stream>>>(slotA, slotB, cA, cB);
        scan2_kernel<<<(HID + 255) / 256, blk, 0, stream>>>(cA, cB, cH0);
        scan3_kernel<<<(NCH * HID) / 256, blk, 0, stream>>>(slotA, slotB, cH0, slotC);
        // xh3 = silu(xb @ input_w[:HID].T) * xh2(slotB) -> slotA
        gemm_mfma<2><<<dim3(TT / 128, HID / 128), blk, 0, stream>>>(
            xb, iwp, iwN, slotA, (float*)nullptr, slotB, TT, HID, DIMW);
        // k|v -> slotB [T][768]
        gemm_mfma<0><<<dim3(TT / 128, (2 * DD) / 128), blk, 0, stream>>>(
            slotA, wkvp, kvN, slotB, (float*)nullptr, (const float*)nullptr, TT, 2 * DD, HID);
        // segment attention -> membuf
        attn1_kernel<<<SSEG, blk, 0, stream>>>(slotB, qbuf, membuf);
        // xr = gelu(xh3)*h -> slotA in-place (reads slotC)
        gelu_mul_kernel<<<ewBlocks, blk, 0, stream>>>(slotA, slotC);
        // rq = xr @ rq_w.T -> slotB
        gemm_mfma<0><<<dim3(TT / 128, DD / 128), blk, 0, stream>>>(
            slotA, rqwp, rqN, slotB, (float*)nullptr, (const float*)nullptr, TT, DD, HID);
        // rk = mem @ rk_w.T ; rv = mem @ rv_w.T (tiny, fp32 path)
        gemm32<0, 64, 64><<<dim3(1, DD / 64), blk, 0, stream>>>(
            membuf, rk_w, rkbuf, (float*)nullptr, (const float*)nullptr, SSEG, DD, DD);
        gemm32<0, 64, 64><<<dim3(1, HID / 64), blk, 0, stream>>>(
            membuf, rv_w, rvbuf, (float*)nullptr, (const float*)nullptr, SSEG, HID, DD);
        // cross attention + gate -> out2(slotC)
        attn2_kernel<<<TT, blk, 0, stream>>>(slotB, rkbuf, rvbuf, slotA, wg_w, slotC);
        // final projection -> d_out
        gemm_mfma<0><<<dim3(TT / 128, DIMW / 128), blk, 0, stream>>>(
            slotC, owp, owN, outb, (float*)nullptr, (const float*)nullptr, TT, DIMW, HID);
    }
}